// Round 2
// baseline (1410.702 us; speedup 1.0000x reference)
//
#include <hip/hip_runtime.h>

// DecoderBlock: self-attn (softmax over QUERY axis) + cross-attn + FFN, 3 LNs.
// All GEMMs: bf16 MFMA 16x16x32, NT form (both operands K-contiguous).
// Weights pre-transposed+converted to bf16 [N,K] each call.
// Workspace map (233 MB total, explicit offsets, time-shared):
//   [0,64M)    weights: self qkv+p @0..32M, cross qkv+p @32..64M; later FF w1T@0(32M) w2T@32M(32M)
//   [64,72M)   xb    [72,80M) encb   [80,88M) x1b   [88,96M) x2b      (bf16 acts)
//   [96,112M)  x1f   [112,128M) x2f                                   (f32 acts)
//   [128,136M) Qb  [136,144M) Kb  [144,152M) Vb  [152,160M) VTb  [160,168M) attnb
//   [168M]     ovec (128K)
//   [169,233M) scores bf16 (64M); aliases: projf f32(16M)@169M, h1 bf16(32M)@169M, fff f32(16M)@201M

typedef unsigned short bhalf;   // bf16 bit pattern
typedef __attribute__((ext_vector_type(8))) short short8;
typedef __attribute__((ext_vector_type(4))) float f32x4;
typedef __attribute__((ext_vector_type(4))) unsigned int u32x4;

static constexpr int LDP = 72;   // LDS padded row (bf16); 144B = 9*16 -> aligned b128, ~2-way banks (free)

static __device__ __forceinline__ unsigned short f2bu(float x) {
  unsigned int u = __float_as_uint(x);
  unsigned int r = (u + 0x7fffu + ((u >> 16) & 1u)) >> 16;
  return (unsigned short)r;
}
static __device__ __forceinline__ float b2f(unsigned short h) {
  return __uint_as_float(((unsigned int)h) << 16);
}

// ---------------- f32 -> bf16 elementwise ----------------
__global__ __launch_bounds__(256) void k_convert(const float* __restrict__ in,
                                                 bhalf* __restrict__ out) {
  long i = ((long)blockIdx.x * 256 + threadIdx.x) * 8;
  f32x4 a = *(const f32x4*)(in + i);
  f32x4 b = *(const f32x4*)(in + i + 4);
  unsigned int w0 = f2bu(a[0]) | ((unsigned int)f2bu(a[1]) << 16);
  unsigned int w1 = f2bu(a[2]) | ((unsigned int)f2bu(a[3]) << 16);
  unsigned int w2 = f2bu(b[0]) | ((unsigned int)f2bu(b[1]) << 16);
  unsigned int w3 = f2bu(b[2]) | ((unsigned int)f2bu(b[3]) << 16);
  u32x4 v = {w0, w1, w2, w3};
  *(u32x4*)(out + i) = v;
}

// ---------------- f32 [R,C] -> bf16 [C,R] tiled transpose (batched) ----------------
__global__ __launch_bounds__(256) void k_transpose_f2b(
    const float* __restrict__ in, long ld_in, long in_bs,
    bhalf* __restrict__ out, long ld_out, long out_bs) {
  __shared__ float t[32][33];
  in  += (long)blockIdx.z * in_bs;
  out += (long)blockIdx.z * out_bs;
  const long c0 = (long)blockIdx.x * 32, r0 = (long)blockIdx.y * 32;
  const int tx = threadIdx.x & 31, ty = threadIdx.x >> 5;
#pragma unroll
  for (int i = 0; i < 4; ++i) {
    int r = ty + i * 8;
    t[r][tx] = in[(r0 + r) * ld_in + c0 + tx];
  }
  __syncthreads();
#pragma unroll
  for (int i = 0; i < 4; ++i) {
    int c = ty + i * 8;
    out[(c0 + c) * ld_out + r0 + tx] = f2bu(t[tx][c]);
  }
}

// ---------------- bf16 [R,C] -> bf16 [C,R] tiled transpose (two-level batch) ----------------
__global__ __launch_bounds__(256) void k_transpose_b2b(
    const bhalf* __restrict__ in, long ld_in, long in_bo, long in_bi, int inner,
    bhalf* __restrict__ out, long ld_out, long out_bs) {
  __shared__ bhalf t[32][34];
  const int z = blockIdx.z;
  in  += (long)(z / inner) * in_bo + (long)(z % inner) * in_bi;
  out += (long)z * out_bs;
  const long c0 = (long)blockIdx.x * 32, r0 = (long)blockIdx.y * 32;
  const int tx = threadIdx.x & 31, ty = threadIdx.x >> 5;
#pragma unroll
  for (int i = 0; i < 4; ++i) {
    int r = ty + i * 8;
    t[r][tx] = in[(r0 + r) * ld_in + c0 + tx];
  }
  __syncthreads();
#pragma unroll
  for (int i = 0; i < 4; ++i) {
    int c = ty + i * 8;
    out[(c0 + c) * ld_out + r0 + tx] = t[tx][c];
  }
}

// ---------------- per-column (query-axis) softmax stats over bf16 scores ----------------
// ovec[z*1024 + k] = m + log(sum_q exp(s[q,k]-m))
__global__ __launch_bounds__(256) void k_smstats(const bhalf* __restrict__ sc,
                                                 float* __restrict__ ovec) {
  const int col = blockIdx.x * 256 + threadIdx.x;            // 0..1023 (key index)
  const long base = (long)blockIdx.y * (1024L * 1024L) + col;
  float m = -1e30f, l = 0.0f;
  for (int q = 0; q < 1024; ++q) {
    float v = b2f(sc[base + (long)q * 1024]);
    float nm = fmaxf(m, v);
    l = l * __expf(m - nm) + __expf(v - nm);
    m = nm;
  }
  ovec[blockIdx.y * 1024 + col] = m + __logf(l);
}

// ---------------- generic NT GEMM: C[M,N] = A[M,K] @ BT[N,K]^T ----------------
// 128x128 tile, BK=32, 4 waves, mfma_f32_16x16x32_bf16.
// A_EXP: A is bf16 scores; staged as bf16(exp(a - ovec[z*K + k])).
template<int A_EXP, int OUT_BF16, int RELU, int BIAS>
__global__ __launch_bounds__(256) void k_gemm(
    const bhalf* __restrict__ Ap, long lda,
    const bhalf* __restrict__ BTp, long ldb,
    void* __restrict__ Cp, long ldc,
    const float* __restrict__ bias,
    const float* __restrict__ ovec,
    int K, float out_scale,
    long a_bo, long a_bi, long b_bo, long b_bi, long c_bo, long c_bi, int inner) {
  __shared__ alignas(16) bhalf As[128 * LDP];
  __shared__ alignas(16) bhalf Bs[128 * LDP];
  const int tid = threadIdx.x;
  const int z = blockIdx.z;
  const int zo = z / inner, zi = z % inner;
  const long aoff = (long)zo * a_bo + (long)zi * a_bi;
  const long boff = (long)zo * b_bo + (long)zi * b_bi;
  const long coff = (long)zo * c_bo + (long)zi * c_bi;
  const long arow0 = (long)blockIdx.y * 128;
  const long brow0 = (long)blockIdx.x * 128;

  f32x4 acc[4][4];
#pragma unroll
  for (int i = 0; i < 4; ++i)
#pragma unroll
    for (int j = 0; j < 4; ++j) acc[i][j] = (f32x4){0.f, 0.f, 0.f, 0.f};

  const int wid = tid >> 6;
  const int lane = tid & 63;
  const int wr = wid >> 1, wc = wid & 1;
  const int lr = lane & 15;
  const int lk = lane >> 4;

  for (int k0 = 0; k0 < K; k0 += 32) {
    const bhalf* Ab = Ap + aoff + arow0 * lda + k0;
    if (!A_EXP) {
#pragma unroll
      for (int it = 0; it < 2; ++it) {
        int slot = tid + it * 256;
        int row = slot >> 2;
        int ko = (slot & 3) << 3;
        u32x4 v = *(const u32x4*)(Ab + (long)row * lda + ko);
        *(u32x4*)(As + row * LDP + ko) = v;
      }
    } else {
      const float* oz = ovec + (long)z * K + k0;
#pragma unroll
      for (int it = 0; it < 2; ++it) {
        int slot = tid + it * 256;
        int row = slot >> 2;
        int ko = (slot & 3) << 3;
        short8 v = *(const short8*)(Ab + (long)row * lda + ko);
        unsigned int w[4];
#pragma unroll
        for (int p = 0; p < 4; ++p) {
          float f0 = __expf(b2f((unsigned short)v[2 * p])     - oz[ko + 2 * p]);
          float f1 = __expf(b2f((unsigned short)v[2 * p + 1]) - oz[ko + 2 * p + 1]);
          w[p] = f2bu(f0) | ((unsigned int)f2bu(f1) << 16);
        }
        u32x4 pk = {w[0], w[1], w[2], w[3]};
        *(u32x4*)(As + row * LDP + ko) = pk;
      }
    }
    {
      const bhalf* Bb = BTp + boff + brow0 * ldb + k0;
#pragma unroll
      for (int it = 0; it < 2; ++it) {
        int slot = tid + it * 256;
        int row = slot >> 2;
        int ko = (slot & 3) << 3;
        u32x4 v = *(const u32x4*)(Bb + (long)row * ldb + ko);
        *(u32x4*)(Bs + row * LDP + ko) = v;
      }
    }
    __syncthreads();
    short8 af[4], bf_[4];
#pragma unroll
    for (int i = 0; i < 4; ++i)
      af[i] = *(const short8*)(As + (wr * 64 + i * 16 + lr) * LDP + lk * 8);
#pragma unroll
    for (int j = 0; j < 4; ++j)
      bf_[j] = *(const short8*)(Bs + (wc * 64 + j * 16 + lr) * LDP + lk * 8);
#pragma unroll
    for (int i = 0; i < 4; ++i)
#pragma unroll
      for (int j = 0; j < 4; ++j)
        acc[i][j] = __builtin_amdgcn_mfma_f32_16x16x32_bf16(af[i], bf_[j], acc[i][j], 0, 0, 0);
    __syncthreads();
  }

  const int lq = lane >> 4;
#pragma unroll
  for (int j = 0; j < 4; ++j) {
    long col = brow0 + wc * 64 + j * 16 + lr;
    float bv = BIAS ? bias[col] : 0.0f;
#pragma unroll
    for (int i = 0; i < 4; ++i) {
#pragma unroll
      for (int r = 0; r < 4; ++r) {
        long row = arow0 + wr * 64 + i * 16 + lq * 4 + r;
        float x = acc[i][j][r] * out_scale + bv;
        if (RELU) x = fmaxf(x, 0.0f);
        if (OUT_BF16) ((bhalf*)Cp)[coff + row * ldc + col] = f2bu(x);
        else          ((float*)Cp)[coff + row * ldc + col] = x;
      }
    }
  }
}

// ---------------- fused residual + LayerNorm over D=2048 ----------------
template<int WB>
__global__ __launch_bounds__(256) void k_ln(const float* __restrict__ a,
                                            const float* __restrict__ r,
                                            const float* __restrict__ g,
                                            const float* __restrict__ b,
                                            float* __restrict__ outf,
                                            bhalf* __restrict__ outb) {
  const int row = blockIdx.x, tid = threadIdx.x;
  const long base = (long)row * 2048 + tid * 8;
  f32x4 v0 = *(const f32x4*)(a + base);
  f32x4 v1 = *(const f32x4*)(a + base + 4);
  f32x4 r0 = *(const f32x4*)(r + base);
  f32x4 r1 = *(const f32x4*)(r + base + 4);
  float x[8];
#pragma unroll
  for (int j = 0; j < 4; ++j) { x[j] = v0[j] + r0[j]; x[4 + j] = v1[j] + r1[j]; }
  float s = 0.f, s2 = 0.f;
#pragma unroll
  for (int j = 0; j < 8; ++j) { s += x[j]; s2 += x[j] * x[j]; }
#pragma unroll
  for (int off = 32; off; off >>= 1) {
    s += __shfl_down(s, off, 64);
    s2 += __shfl_down(s2, off, 64);
  }
  __shared__ float sh[8];
  const int wid = tid >> 6, lane = tid & 63;
  if (lane == 0) { sh[wid] = s; sh[4 + wid] = s2; }
  __syncthreads();
  s = sh[0] + sh[1] + sh[2] + sh[3];
  s2 = sh[4] + sh[5] + sh[6] + sh[7];
  const float mean = s * (1.0f / 2048.0f);
  const float var = s2 * (1.0f / 2048.0f) - mean * mean;
  const float inv = rsqrtf(var + 1e-5f);
#pragma unroll
  for (int j = 0; j < 8; ++j) {
    int cidx = tid * 8 + j;
    float y = (x[j] - mean) * inv * g[cidx] + b[cidx];
    outf[base + j] = y;
    if (WB) outb[base + j] = f2bu(y);
  }
}

extern "C" void kernel_launch(void* const* d_in, const int* in_sizes, int n_in,
                              void* d_out, int out_size, void* d_ws, size_t ws_size,
                              hipStream_t stream) {
  const long S = 1024, D = 2048, DFF = 8192;

  const float* X    = (const float*)d_in[0];
  const float* ENC  = (const float*)d_in[1];
  const float* WQ1  = (const float*)d_in[2];
  const float* WK1  = (const float*)d_in[3];
  const float* WV1  = (const float*)d_in[4];
  const float* BQ1  = (const float*)d_in[5];
  const float* BK1  = (const float*)d_in[6];
  const float* BV1  = (const float*)d_in[7];
  const float* WP1  = (const float*)d_in[8];
  const float* BP1  = (const float*)d_in[9];
  const float* WQ2  = (const float*)d_in[10];
  const float* WK2  = (const float*)d_in[11];
  const float* WV2  = (const float*)d_in[12];
  const float* BQ2  = (const float*)d_in[13];
  const float* BK2  = (const float*)d_in[14];
  const float* BV2  = (const float*)d_in[15];
  const float* WP2  = (const float*)d_in[16];
  const float* BP2  = (const float*)d_in[17];
  const float* LN1G = (const float*)d_in[18];
  const float* LN1B = (const float*)d_in[19];
  const float* LN2G = (const float*)d_in[20];
  const float* LN2B = (const float*)d_in[21];
  const float* LN3G = (const float*)d_in[22];
  const float* LN3B = (const float*)d_in[23];
  const float* WF1  = (const float*)d_in[24];
  const float* BF1  = (const float*)d_in[25];
  const float* WF2  = (const float*)d_in[26];
  const float* BF2  = (const float*)d_in[27];
  (void)in_sizes; (void)n_in; (void)out_size; (void)ws_size;

  char* ws = (char*)d_ws;
  const size_t MB = 1024 * 1024;
  // weight region [0,64M)
  bhalf* wq1T = (bhalf*)(ws + 0 * MB);
  bhalf* wk1T = (bhalf*)(ws + 8 * MB);
  bhalf* wv1T = (bhalf*)(ws + 16 * MB);
  bhalf* wp1T = (bhalf*)(ws + 24 * MB);
  bhalf* wq2T = (bhalf*)(ws + 32 * MB);
  bhalf* wk2T = (bhalf*)(ws + 40 * MB);
  bhalf* wv2T = (bhalf*)(ws + 48 * MB);
  bhalf* wp2T = (bhalf*)(ws + 56 * MB);
  bhalf* wf1T = (bhalf*)(ws + 0 * MB);    // alias (after cross proj)
  bhalf* wf2T = (bhalf*)(ws + 32 * MB);   // alias (after cross proj)
  // activations
  bhalf* xb   = (bhalf*)(ws + 64 * MB);
  bhalf* encb = (bhalf*)(ws + 72 * MB);
  bhalf* x1b  = (bhalf*)(ws + 80 * MB);
  bhalf* x2b  = (bhalf*)(ws + 88 * MB);
  float* x1f  = (float*)(ws + 96 * MB);
  float* x2f  = (float*)(ws + 112 * MB);
  bhalf* Qb   = (bhalf*)(ws + 128 * MB);
  bhalf* Kb   = (bhalf*)(ws + 136 * MB);
  bhalf* Vb   = (bhalf*)(ws + 144 * MB);
  bhalf* VTb  = (bhalf*)(ws + 152 * MB);
  bhalf* attnb= (bhalf*)(ws + 160 * MB);
  float* ovec = (float*)(ws + 168 * MB);           // 128 KB
  bhalf* scores = (bhalf*)(ws + 169 * MB);         // 64 MB bf16 [32][1024][1024]
  float* projf  = (float*)(ws + 169 * MB);         // alias, 16 MB (after PV)
  bhalf* h1     = (bhalf*)(ws + 169 * MB);         // alias, 32 MB (FF intermediate)
  float* fff    = (float*)(ws + 201 * MB);         // alias, 16 MB
  // total: 233 MB

  const float SCL = 0.08838834764831845f;  // 1/sqrt(128)

  // ---- convert activations ----
  k_convert<<<dim3(2048), 256, 0, stream>>>(X, xb);
  k_convert<<<dim3(2048), 256, 0, stream>>>(ENC, encb);
  // ---- transpose+convert attention weights to [N,K] bf16 ----
  k_transpose_f2b<<<dim3(4, 64, 16), 256, 0, stream>>>(WQ1, 128, D * 128, wq1T, D, 128 * D);
  k_transpose_f2b<<<dim3(4, 64, 16), 256, 0, stream>>>(WK1, 128, D * 128, wk1T, D, 128 * D);
  k_transpose_f2b<<<dim3(4, 64, 16), 256, 0, stream>>>(WV1, 128, D * 128, wv1T, D, 128 * D);
  k_transpose_f2b<<<dim3(64, 64, 1), 256, 0, stream>>>(WP1, D, 0, wp1T, D, 0);
  k_transpose_f2b<<<dim3(4, 64, 16), 256, 0, stream>>>(WQ2, 128, D * 128, wq2T, D, 128 * D);
  k_transpose_f2b<<<dim3(4, 64, 16), 256, 0, stream>>>(WK2, 128, D * 128, wk2T, D, 128 * D);
  k_transpose_f2b<<<dim3(4, 64, 16), 256, 0, stream>>>(WV2, 128, D * 128, wv2T, D, 128 * D);
  k_transpose_f2b<<<dim3(64, 64, 1), 256, 0, stream>>>(WP2, D, 0, wp2T, D, 0);

  // ================= self-attention =================
  k_gemm<0,1,0,1><<<dim3(16,16,1), 256, 0, stream>>>(xb, D, wq1T, D, Qb, D, BQ1, nullptr,
      (int)D, 1.0f, 0,0, 0,0, 0,0, 1);
  k_gemm<0,1,0,1><<<dim3(16,16,1), 256, 0, stream>>>(xb, D, wk1T, D, Kb, D, BK1, nullptr,
      (int)D, 1.0f, 0,0, 0,0, 0,0, 1);
  k_gemm<0,1,0,1><<<dim3(16,16,1), 256, 0, stream>>>(xb, D, wv1T, D, Vb, D, BV1, nullptr,
      (int)D, 1.0f, 0,0, 0,0, 0,0, 1);
  k_transpose_b2b<<<dim3(4, 32, 32), 256, 0, stream>>>(Vb, D, S * D, 128, 16, VTb, S, 128 * S);
  // scores[z=bh] = Qh @ Kh^T * scl   (bf16, [1024,1024] per bh)
  k_gemm<0,1,0,0><<<dim3(8,8,32), 256, 0, stream>>>(Qb, D, Kb, D, scores, S, nullptr, nullptr,
      128, SCL, S * D, 128, S * D, 128, 16L * S * S, S * S, 16);
  k_smstats<<<dim3(4, 32), 256, 0, stream>>>(scores, ovec);
  // attn_out[z] = exp(scores - o[k]) @ Vh   (bf16, concat-head layout)
  k_gemm<1,1,0,0><<<dim3(1,8,32), 256, 0, stream>>>(scores, S, VTb, S, attnb, D, nullptr, ovec,
      (int)S, 1.0f, 16L * S * S, S * S, 16L * 128 * S, 128 * S, S * D, 128, 16);
  k_gemm<0,0,0,1><<<dim3(16,16,1), 256, 0, stream>>>(attnb, D, wp1T, D, projf, D, BP1, nullptr,
      (int)D, 1.0f, 0,0, 0,0, 0,0, 1);
  k_ln<1><<<dim3(2048), 256, 0, stream>>>(X, projf, LN1G, LN1B, x1f, x1b);

  // ================= cross-attention (Q from encoder, K/V from x1) =================
  k_gemm<0,1,0,1><<<dim3(16,16,1), 256, 0, stream>>>(encb, D, wq2T, D, Qb, D, BQ2, nullptr,
      (int)D, 1.0f, 0,0, 0,0, 0,0, 1);
  k_gemm<0,1,0,1><<<dim3(16,16,1), 256, 0, stream>>>(x1b, D, wk2T, D, Kb, D, BK2, nullptr,
      (int)D, 1.0f, 0,0, 0,0, 0,0, 1);
  k_gemm<0,1,0,1><<<dim3(16,16,1), 256, 0, stream>>>(x1b, D, wv2T, D, Vb, D, BV2, nullptr,
      (int)D, 1.0f, 0,0, 0,0, 0,0, 1);
  k_transpose_b2b<<<dim3(4, 32, 32), 256, 0, stream>>>(Vb, D, S * D, 128, 16, VTb, S, 128 * S);
  k_gemm<0,1,0,0><<<dim3(8,8,32), 256, 0, stream>>>(Qb, D, Kb, D, scores, S, nullptr, nullptr,
      128, SCL, S * D, 128, S * D, 128, 16L * S * S, S * S, 16);
  k_smstats<<<dim3(4, 32), 256, 0, stream>>>(scores, ovec);
  k_gemm<1,1,0,0><<<dim3(1,8,32), 256, 0, stream>>>(scores, S, VTb, S, attnb, D, nullptr, ovec,
      (int)S, 1.0f, 16L * S * S, S * S, 16L * 128 * S, 128 * S, S * D, 128, 16);
  k_gemm<0,0,0,1><<<dim3(16,16,1), 256, 0, stream>>>(attnb, D, wp2T, D, projf, D, BP2, nullptr,
      (int)D, 1.0f, 0,0, 0,0, 0,0, 1);
  k_ln<1><<<dim3(2048), 256, 0, stream>>>(x1f, projf, LN2G, LN2B, x2f, x2b);

  // ================= feed-forward =================
  // FF weight transposes only now (they overwrite the attention-weight region)
  k_transpose_f2b<<<dim3(256, 64, 1), 256, 0, stream>>>(WF1, DFF, 0, wf1T, D, 0);
  k_transpose_f2b<<<dim3(64, 256, 1), 256, 0, stream>>>(WF2, D, 0, wf2T, DFF, 0);
  k_gemm<0,1,1,1><<<dim3(64,16,1), 256, 0, stream>>>(x2b, D, wf1T, D, h1, DFF, BF1, nullptr,
      (int)D, 1.0f, 0,0, 0,0, 0,0, 1);
  k_gemm<0,0,0,1><<<dim3(16,16,1), 256, 0, stream>>>(h1, DFF, wf2T, DFF, fff, D, BF2, nullptr,
      (int)DFF, 1.0f, 0,0, 0,0, 0,0, 1);
  k_ln<0><<<dim3(2048), 256, 0, stream>>>(x2f, fff, LN3G, LN3B, (float*)d_out, nullptr);
}

// Round 3
// 1076.170 us; speedup vs baseline: 1.3109x; 1.3109x over previous
//
#include <hip/hip_runtime.h>

// DecoderBlock, round 3: m97-structure GEMM (global_load_lds + linear LDS),
// fused QKV (N=6144), split-K proj/FF2 with LN-side reduction, P materialization.
// Workspace map (233 MB):
//   [0,64M)    weights: wq1T@0 wk1T@8 wv1T@16 wp1T@24 wq2T@32 wk2T@40 wv2T@48 wp2T@56
//              (FF phase aliases: wf1T@0 (32M), wf2T@32M (32M))
//   [64,72M)   xb   [72,80M) encb   [80,88M) x1b   [88,96M) x2b      (bf16)
//   [96,112M)  x1f  [112,128M) x2f                                   (f32)
//   [128,152M) Cq [2048][6144] bf16 (self QKV out) / cross: Ckv@128(16M) Qb2@144(8M)
//              FF phase: h1 [2048][8192] bf16 (32M @128-160)
//   [152,160M) VTb [32][128][1024] bf16
//   [160,168M) attnb [2048][2048] bf16
//   [168M]     ovec 128K | qkvb1 24K @+128K | kvb2 16K @+160K
//   [169,233M) scores/P bf16 64M; later proj partials [2][2048][2048] f32 (32M);
//              later FF2 partials [4][2048][2048] f32 (64M)

typedef unsigned short bhalf;
typedef __attribute__((ext_vector_type(8))) short short8;
typedef __attribute__((ext_vector_type(4))) float f32x4;
typedef __attribute__((ext_vector_type(4))) unsigned int u32x4;

static __device__ __forceinline__ unsigned short f2bu(float x) {
  unsigned int u = __float_as_uint(x);
  unsigned int r = (u + 0x7fffu + ((u >> 16) & 1u)) >> 16;
  return (unsigned short)r;
}
static __device__ __forceinline__ float b2f(unsigned short h) {
  return __uint_as_float(((unsigned int)h) << 16);
}
static __device__ __forceinline__ void gll16(const void* g, void* l) {
  __builtin_amdgcn_global_load_lds(
      (const __attribute__((address_space(1))) unsigned int*)g,
      (__attribute__((address_space(3))) unsigned int*)l, 16, 0, 0);
}

// ---------------- f32 -> bf16 elementwise ----------------
__global__ __launch_bounds__(256) void k_convert(const float* __restrict__ in,
                                                 bhalf* __restrict__ out) {
  long i = ((long)blockIdx.x * 256 + threadIdx.x) * 8;
  f32x4 a = *(const f32x4*)(in + i);
  f32x4 b = *(const f32x4*)(in + i + 4);
  unsigned int w0 = f2bu(a[0]) | ((unsigned int)f2bu(a[1]) << 16);
  unsigned int w1 = f2bu(a[2]) | ((unsigned int)f2bu(a[3]) << 16);
  unsigned int w2 = f2bu(b[0]) | ((unsigned int)f2bu(b[1]) << 16);
  unsigned int w3 = f2bu(b[2]) | ((unsigned int)f2bu(b[3]) << 16);
  u32x4 v = {w0, w1, w2, w3};
  *(u32x4*)(out + i) = v;
}

// ---------------- bias concat ----------------
__global__ __launch_bounds__(256) void k_cat(float* __restrict__ dst,
                                             const float* __restrict__ s0,
                                             const float* __restrict__ s1,
                                             const float* __restrict__ s2) {
  int i = blockIdx.x * 256 + threadIdx.x;
  const float* s = i < 2048 ? s0 : (i < 4096 ? s1 : s2);
  dst[i] = s[i & 2047];
}

// ---------------- f32 [R,C] -> bf16 [C,R] tiled transpose (batched) ----------------
__global__ __launch_bounds__(256) void k_transpose_f2b(
    const float* __restrict__ in, long ld_in, long in_bs,
    bhalf* __restrict__ out, long ld_out, long out_bs) {
  __shared__ float t[32][33];
  in  += (long)blockIdx.z * in_bs;
  out += (long)blockIdx.z * out_bs;
  const long c0 = (long)blockIdx.x * 32, r0 = (long)blockIdx.y * 32;
  const int tx = threadIdx.x & 31, ty = threadIdx.x >> 5;
#pragma unroll
  for (int i = 0; i < 4; ++i) {
    int r = ty + i * 8;
    t[r][tx] = in[(r0 + r) * ld_in + c0 + tx];
  }
  __syncthreads();
#pragma unroll
  for (int i = 0; i < 4; ++i) {
    int c = ty + i * 8;
    out[(c0 + c) * ld_out + r0 + tx] = f2bu(t[tx][c]);
  }
}

// ---------------- bf16 [R,C] -> bf16 [C,R] tiled transpose (two-level batch) ----------------
__global__ __launch_bounds__(256) void k_transpose_b2b(
    const bhalf* __restrict__ in, long ld_in, long in_bo, long in_bi, int inner,
    bhalf* __restrict__ out, long ld_out, long out_bs) {
  __shared__ bhalf t[32][34];
  const int z = blockIdx.z;
  in  += (long)(z / inner) * in_bo + (long)(z % inner) * in_bi;
  out += (long)z * out_bs;
  const long c0 = (long)blockIdx.x * 32, r0 = (long)blockIdx.y * 32;
  const int tx = threadIdx.x & 31, ty = threadIdx.x >> 5;
#pragma unroll
  for (int i = 0; i < 4; ++i) {
    int r = ty + i * 8;
    t[r][tx] = in[(r0 + r) * ld_in + c0 + tx];
  }
  __syncthreads();
#pragma unroll
  for (int i = 0; i < 4; ++i) {
    int c = ty + i * 8;
    out[(c0 + c) * ld_out + r0 + tx] = t[tx][c];
  }
}

// ---------------- query-axis softmax stats: ovec[z,k] = m + log(sum_q exp(s[q,k]-m)) ----------------
// grid (16, 32): block = 64 cols x 4 q-groups of 256 rows
__global__ __launch_bounds__(256) void k_smstats(const bhalf* __restrict__ sc,
                                                 float* __restrict__ ovec) {
  const int c = threadIdx.x & 63, qg = threadIdx.x >> 6;
  const int col = blockIdx.x * 64 + c;
  const bhalf* p = sc + (long)blockIdx.y * (1024L * 1024L) + col + (long)qg * 256 * 1024;
  float m = -1e30f, l = 0.0f;
#pragma unroll 8
  for (int q = 0; q < 256; ++q) {
    float v = b2f(p[(long)q * 1024]);
    float nm = fmaxf(m, v);
    l = l * __expf(m - nm) + __expf(v - nm);
    m = nm;
  }
  __shared__ float sm[4][64], sl[4][64];
  sm[qg][c] = m; sl[qg][c] = l;
  __syncthreads();
  if (qg == 0) {
    float M = m;
#pragma unroll
    for (int g2 = 1; g2 < 4; ++g2) M = fmaxf(M, sm[g2][c]);
    float L = 0.0f;
#pragma unroll
    for (int g2 = 0; g2 < 4; ++g2) L += sl[g2][c] * __expf(sm[g2][c] - M);
    ovec[blockIdx.y * 1024 + col] = M + __logf(L);
  }
}

// ---------------- P = exp(s - ovec[col]) in place ----------------
__global__ __launch_bounds__(256) void k_pexp(bhalf* __restrict__ sc,
                                              const float* __restrict__ ovec) {
  long i = ((long)blockIdx.x * 256 + threadIdx.x) * 8;
  const int z = (int)(i >> 20);
  const int col = (int)(i & 1023);
  short8 v = *(const short8*)(sc + i);
  const float* o = ovec + z * 1024 + col;
  f32x4 o0 = *(const f32x4*)o;
  f32x4 o1 = *(const f32x4*)(o + 4);
  unsigned int w[4];
#pragma unroll
  for (int p = 0; p < 2; ++p) {
    w[p] = f2bu(__expf(b2f((unsigned short)v[2 * p]) - o0[2 * p])) |
           ((unsigned int)f2bu(__expf(b2f((unsigned short)v[2 * p + 1]) - o0[2 * p + 1])) << 16);
    w[2 + p] = f2bu(__expf(b2f((unsigned short)v[4 + 2 * p]) - o1[2 * p])) |
           ((unsigned int)f2bu(__expf(b2f((unsigned short)v[4 + 2 * p + 1]) - o1[2 * p + 1])) << 16);
  }
  u32x4 pk = {w[0], w[1], w[2], w[3]};
  *(u32x4*)(sc + i) = pk;
}

// ---------------- NT GEMM, m97 structure: C[M,N] = A[M,K] @ BT[N,K]^T ----------------
// 128x128 tile, BK=32, 4 waves, global_load_lds staging into linear LDS [128][32].
template<int OUT_BF16, int RELU, int BIAS>
__global__ __launch_bounds__(256) void k_gemm(
    const bhalf* __restrict__ Ap, long lda,
    const bhalf* __restrict__ BTp, long ldb,
    void* __restrict__ Cp, long ldc,
    const float* __restrict__ bias,
    int K, float out_scale,
    long a_bo, long a_bi, long b_bo, long b_bi, long c_bo, long c_bi, int inner) {
  __shared__ alignas(16) bhalf As[128 * 32];
  __shared__ alignas(16) bhalf Bs[128 * 32];
  const int tid = threadIdx.x;
  const int z = blockIdx.z;
  const int zo = z / inner, zi = z % inner;
  const bhalf* Abase = Ap + (long)zo * a_bo + (long)zi * a_bi + (long)blockIdx.y * 128 * lda;
  const bhalf* Bbase = BTp + (long)zo * b_bo + (long)zi * b_bi + (long)blockIdx.x * 128 * ldb;
  const long coff = (long)zo * c_bo + (long)zi * c_bi;

  const int wid = tid >> 6, lane = tid & 63;
  const int wr = wid >> 1, wc = wid & 1;
  const int lr = lane & 15, lk = lane >> 4;
  // staging: wave covers chunks (wid*2, wid*2+1); lane l -> row c*16 + (l>>2), kpart (l&3)*8
  const int srow0 = wid * 32 + (lane >> 2);
  const int srow1 = srow0 + 16;
  const int skq = (lane & 3) * 8;

  f32x4 acc[4][4];
#pragma unroll
  for (int i = 0; i < 4; ++i)
#pragma unroll
    for (int j = 0; j < 4; ++j) acc[i][j] = (f32x4){0.f, 0.f, 0.f, 0.f};

  for (int k0 = 0; k0 < K; k0 += 32) {
    gll16(Abase + (long)srow0 * lda + k0 + skq, As + srow0 * 32 + skq);
    gll16(Abase + (long)srow1 * lda + k0 + skq, As + srow1 * 32 + skq);
    gll16(Bbase + (long)srow0 * ldb + k0 + skq, Bs + srow0 * 32 + skq);
    gll16(Bbase + (long)srow1 * ldb + k0 + skq, Bs + srow1 * 32 + skq);
    __syncthreads();
    short8 af[4], bf_[4];
#pragma unroll
    for (int i = 0; i < 4; ++i)
      af[i] = *(const short8*)(As + (wr * 64 + i * 16 + lr) * 32 + lk * 8);
#pragma unroll
    for (int j = 0; j < 4; ++j)
      bf_[j] = *(const short8*)(Bs + (wc * 64 + j * 16 + lr) * 32 + lk * 8);
#pragma unroll
    for (int i = 0; i < 4; ++i)
#pragma unroll
      for (int j = 0; j < 4; ++j)
        acc[i][j] = __builtin_amdgcn_mfma_f32_16x16x32_bf16(af[i], bf_[j], acc[i][j], 0, 0, 0);
    __syncthreads();
  }

#pragma unroll
  for (int j = 0; j < 4; ++j) {
    long col = (long)blockIdx.x * 128 + wc * 64 + j * 16 + lr;
    float bv = BIAS ? bias[col] : 0.0f;
#pragma unroll
    for (int i = 0; i < 4; ++i) {
#pragma unroll
      for (int r = 0; r < 4; ++r) {
        long row = (long)blockIdx.y * 128 + wr * 64 + i * 16 + lk * 4 + r;
        float x = acc[i][j][r] * out_scale + bv;
        if (RELU) x = fmaxf(x, 0.0f);
        if (OUT_BF16) ((bhalf*)Cp)[coff + row * ldc + col] = f2bu(x);
        else          ((float*)Cp)[coff + row * ldc + col] = x;
      }
    }
  }
}

// ---------------- residual + NPART partials + column-bias + LayerNorm (D=2048) ----------------
template<int NPART, int WB>
__global__ __launch_bounds__(256) void k_ln(
    const float* __restrict__ r, const float* __restrict__ p0, const float* __restrict__ p1,
    const float* __restrict__ p2, const float* __restrict__ p3,
    const float* __restrict__ cb, const float* __restrict__ g, const float* __restrict__ b,
    float* __restrict__ outf, bhalf* __restrict__ outb) {
  const int row = blockIdx.x, tid = threadIdx.x;
  const long base = (long)row * 2048 + tid * 8;
  float x[8];
#pragma unroll
  for (int h = 0; h < 2; ++h) {
    f32x4 rv = *(const f32x4*)(r + base + h * 4);
    f32x4 c0 = *(const f32x4*)(cb + tid * 8 + h * 4);
    f32x4 q0 = *(const f32x4*)(p0 + base + h * 4);
    f32x4 q1 = *(const f32x4*)(p1 + base + h * 4);
#pragma unroll
    for (int j = 0; j < 4; ++j) x[h * 4 + j] = rv[j] + c0[j] + q0[j] + q1[j];
    if (NPART == 4) {
      f32x4 q2 = *(const f32x4*)(p2 + base + h * 4);
      f32x4 q3 = *(const f32x4*)(p3 + base + h * 4);
#pragma unroll
      for (int j = 0; j < 4; ++j) x[h * 4 + j] += q2[j] + q3[j];
    }
  }
  float s = 0.f, s2 = 0.f;
#pragma unroll
  for (int j = 0; j < 8; ++j) { s += x[j]; s2 += x[j] * x[j]; }
#pragma unroll
  for (int off = 32; off; off >>= 1) {
    s += __shfl_down(s, off, 64);
    s2 += __shfl_down(s2, off, 64);
  }
  __shared__ float sh[8];
  const int wid = tid >> 6, lane = tid & 63;
  if (lane == 0) { sh[wid] = s; sh[4 + wid] = s2; }
  __syncthreads();
  s = sh[0] + sh[1] + sh[2] + sh[3];
  s2 = sh[4] + sh[5] + sh[6] + sh[7];
  const float mean = s * (1.0f / 2048.0f);
  const float var = s2 * (1.0f / 2048.0f) - mean * mean;
  const float inv = rsqrtf(var + 1e-5f);
#pragma unroll
  for (int j = 0; j < 8; ++j) {
    int cidx = tid * 8 + j;
    float y = (x[j] - mean) * inv * g[cidx] + b[cidx];
    outf[base + j] = y;
    if (WB) outb[base + j] = f2bu(y);
  }
}

extern "C" void kernel_launch(void* const* d_in, const int* in_sizes, int n_in,
                              void* d_out, int out_size, void* d_ws, size_t ws_size,
                              hipStream_t stream) {
  const long S = 1024, D = 2048, DFF = 8192;

  const float* X    = (const float*)d_in[0];
  const float* ENC  = (const float*)d_in[1];
  const float* WQ1  = (const float*)d_in[2];
  const float* WK1  = (const float*)d_in[3];
  const float* WV1  = (const float*)d_in[4];
  const float* BQ1  = (const float*)d_in[5];
  const float* BK1  = (const float*)d_in[6];
  const float* BV1  = (const float*)d_in[7];
  const float* WP1  = (const float*)d_in[8];
  const float* BP1  = (const float*)d_in[9];
  const float* WQ2  = (const float*)d_in[10];
  const float* WK2  = (const float*)d_in[11];
  const float* WV2  = (const float*)d_in[12];
  const float* BQ2  = (const float*)d_in[13];
  const float* BK2  = (const float*)d_in[14];
  const float* BV2  = (const float*)d_in[15];
  const float* WP2  = (const float*)d_in[16];
  const float* BP2  = (const float*)d_in[17];
  const float* LN1G = (const float*)d_in[18];
  const float* LN1B = (const float*)d_in[19];
  const float* LN2G = (const float*)d_in[20];
  const float* LN2B = (const float*)d_in[21];
  const float* LN3G = (const float*)d_in[22];
  const float* LN3B = (const float*)d_in[23];
  const float* WF1  = (const float*)d_in[24];
  const float* BF1  = (const float*)d_in[25];
  const float* WF2  = (const float*)d_in[26];
  const float* BF2  = (const float*)d_in[27];
  (void)in_sizes; (void)n_in; (void)out_size; (void)ws_size;

  char* ws = (char*)d_ws;
  const size_t MB = 1024 * 1024;
  bhalf* wq1T = (bhalf*)(ws + 0 * MB);    // qkv1 contiguous -> [6144][2048]
  bhalf* wk1T = (bhalf*)(ws + 8 * MB);
  bhalf* wv1T = (bhalf*)(ws + 16 * MB);
  bhalf* wp1T = (bhalf*)(ws + 24 * MB);
  bhalf* wq2T = (bhalf*)(ws + 32 * MB);
  bhalf* wk2T = (bhalf*)(ws + 40 * MB);   // kv2 contiguous -> [4096][2048]
  bhalf* wv2T = (bhalf*)(ws + 48 * MB);
  bhalf* wp2T = (bhalf*)(ws + 56 * MB);
  bhalf* wf1T = (bhalf*)(ws + 0 * MB);    // alias after cross proj
  bhalf* wf2T = (bhalf*)(ws + 32 * MB);   // alias after cross proj
  bhalf* xb   = (bhalf*)(ws + 64 * MB);
  bhalf* encb = (bhalf*)(ws + 72 * MB);
  bhalf* x1b  = (bhalf*)(ws + 80 * MB);
  bhalf* x2b  = (bhalf*)(ws + 88 * MB);
  float* x1f  = (float*)(ws + 96 * MB);
  float* x2f  = (float*)(ws + 112 * MB);
  bhalf* Cq   = (bhalf*)(ws + 128 * MB);  // [2048][6144] self QKV out (24M)
  bhalf* Ckv  = (bhalf*)(ws + 128 * MB);  // cross: [2048][4096] (16M)
  bhalf* Qb2  = (bhalf*)(ws + 144 * MB);  // cross Q [2048][2048] (8M)
  bhalf* h1   = (bhalf*)(ws + 128 * MB);  // FF: [2048][8192] (32M)
  bhalf* VTb  = (bhalf*)(ws + 152 * MB);  // [32][128][1024]
  bhalf* attnb= (bhalf*)(ws + 160 * MB);
  float* ovec = (float*)(ws + 168 * MB);                 // 128K
  float* qkvb1= (float*)(ws + 168 * MB + 128 * 1024);    // 24K
  float* kvb2 = (float*)(ws + 168 * MB + 160 * 1024);    // 16K
  bhalf* scores = (bhalf*)(ws + 169 * MB);               // 64M ([32][1024][1024])
  float* pp0  = (float*)(ws + 169 * MB);                 // proj partials [2][2048][2048] f32
  float* pp1  = (float*)(ws + 185 * MB);
  float* fp0  = (float*)(ws + 169 * MB);                 // FF2 partials [4][2048][2048] f32
  float* fp1  = (float*)(ws + 185 * MB);
  float* fp2  = (float*)(ws + 201 * MB);
  float* fp3  = (float*)(ws + 217 * MB);

  const float SCL = 0.08838834764831845f;  // 1/sqrt(128)

  // ---- converts + weight transposes + bias concat ----
  k_convert<<<dim3(2048), 256, 0, stream>>>(X, xb);
  k_convert<<<dim3(2048), 256, 0, stream>>>(ENC, encb);
  k_transpose_f2b<<<dim3(4, 64, 16), 256, 0, stream>>>(WQ1, 128, D * 128, wq1T, D, 128 * D);
  k_transpose_f2b<<<dim3(4, 64, 16), 256, 0, stream>>>(WK1, 128, D * 128, wk1T, D, 128 * D);
  k_transpose_f2b<<<dim3(4, 64, 16), 256, 0, stream>>>(WV1, 128, D * 128, wv1T, D, 128 * D);
  k_transpose_f2b<<<dim3(64, 64, 1), 256, 0, stream>>>(WP1, D, 0, wp1T, D, 0);
  k_transpose_f2b<<<dim3(4, 64, 16), 256, 0, stream>>>(WQ2, 128, D * 128, wq2T, D, 128 * D);
  k_transpose_f2b<<<dim3(4, 64, 16), 256, 0, stream>>>(WK2, 128, D * 128, wk2T, D, 128 * D);
  k_transpose_f2b<<<dim3(4, 64, 16), 256, 0, stream>>>(WV2, 128, D * 128, wv2T, D, 128 * D);
  k_transpose_f2b<<<dim3(64, 64, 1), 256, 0, stream>>>(WP2, D, 0, wp2T, D, 0);
  k_cat<<<dim3(24), 256, 0, stream>>>(qkvb1, BQ1, BK1, BV1);
  k_cat<<<dim3(16), 256, 0, stream>>>(kvb2, BK2, BV2, BV2);

  // ================= self-attention =================
  // fused QKV: [2048][6144] = xb @ [wq|wk|wv]^T
  k_gemm<1,0,1><<<dim3(48,16,1), 256, 0, stream>>>(xb, D, wq1T, D, Cq, 6144, qkvb1,
      (int)D, 1.0f, 0,0, 0,0, 0,0, 1);
  k_transpose_b2b<<<dim3(4, 32, 32), 256, 0, stream>>>(Cq + 4096, 6144, S * 6144, 128, 16, VTb, S, 128 * S);
  k_gemm<1,0,0><<<dim3(8,8,32), 256, 0, stream>>>(Cq, 6144, Cq + 2048, 6144, scores, S, nullptr,
      128, SCL, S * 6144, 128, S * 6144, 128, 16L * S * S, S * S, 16);
  k_smstats<<<dim3(16, 32), 256, 0, stream>>>(scores, ovec);
  k_pexp<<<dim3(16384), 256, 0, stream>>>(scores, ovec);
  k_gemm<1,0,0><<<dim3(1,8,32), 256, 0, stream>>>(scores, S, VTb, S, attnb, D, nullptr,
      (int)S, 1.0f, 16L * S * S, S * S, 16L * 128 * S, 128 * S, S * D, 128, 16);
  // proj split-K=2 -> partials
  k_gemm<0,0,0><<<dim3(16,16,2), 256, 0, stream>>>(attnb, D, wp1T, D, pp0, D, nullptr,
      1024, 1.0f, 0, 1024, 0, 1024, 0, (long)D * 2048, 2);
  k_ln<2,1><<<dim3(2048), 256, 0, stream>>>(X, pp0, pp1, nullptr, nullptr, BP1, LN1G, LN1B, x1f, x1b);

  // ================= cross-attention =================
  k_gemm<1,0,1><<<dim3(16,16,1), 256, 0, stream>>>(encb, D, wq2T, D, Qb2, D, BQ2,
      (int)D, 1.0f, 0,0, 0,0, 0,0, 1);
  k_gemm<1,0,1><<<dim3(32,16,1), 256, 0, stream>>>(x1b, D, wk2T, D, Ckv, 4096, kvb2,
      (int)D, 1.0f, 0,0, 0,0, 0,0, 1);
  k_transpose_b2b<<<dim3(4, 32, 32), 256, 0, stream>>>(Ckv + 2048, 4096, S * 4096, 128, 16, VTb, S, 128 * S);
  k_gemm<1,0,0><<<dim3(8,8,32), 256, 0, stream>>>(Qb2, D, Ckv, 4096, scores, S, nullptr,
      128, SCL, S * D, 128, S * 4096, 128, 16L * S * S, S * S, 16);
  k_smstats<<<dim3(16, 32), 256, 0, stream>>>(scores, ovec);
  k_pexp<<<dim3(16384), 256, 0, stream>>>(scores, ovec);
  k_gemm<1,0,0><<<dim3(1,8,32), 256, 0, stream>>>(scores, S, VTb, S, attnb, D, nullptr,
      (int)S, 1.0f, 16L * S * S, S * S, 16L * 128 * S, 128 * S, S * D, 128, 16);
  k_gemm<0,0,0><<<dim3(16,16,2), 256, 0, stream>>>(attnb, D, wp2T, D, pp0, D, nullptr,
      1024, 1.0f, 0, 1024, 0, 1024, 0, (long)D * 2048, 2);
  k_ln<2,1><<<dim3(2048), 256, 0, stream>>>(x1f, pp0, pp1, nullptr, nullptr, BP2, LN2G, LN2B, x2f, x2b);

  // ================= feed-forward =================
  k_transpose_f2b<<<dim3(256, 64, 1), 256, 0, stream>>>(WF1, DFF, 0, wf1T, D, 0);
  k_transpose_f2b<<<dim3(64, 256, 1), 256, 0, stream>>>(WF2, D, 0, wf2T, DFF, 0);
  k_gemm<1,1,1><<<dim3(64,16,1), 256, 0, stream>>>(x2b, D, wf1T, D, h1, DFF, BF1,
      (int)D, 1.0f, 0,0, 0,0, 0,0, 1);
  // FF2 split-K=4 -> partials
  k_gemm<0,0,0><<<dim3(16,16,4), 256, 0, stream>>>(h1, DFF, wf2T, DFF, fp0, D, nullptr,
      2048, 1.0f, 0, 2048, 0, 2048, 0, (long)D * 2048, 4);
  k_ln<4,0><<<dim3(2048), 256, 0, stream>>>(x2f, fp0, fp1, fp2, fp3, BF2, LN3G, LN3B,
      (float*)d_out, nullptr);
}